// Round 2
// baseline (355.194 us; speedup 1.0000x reference)
//
#include <hip/hip_runtime.h>

#define BATCH  8
#define NPTS   16384
#define LVOX   605     // 11*11*5
#define ABINS  8
#define CH     23      // 15 dist features + 8 rot features
#define TLOC   5       // locs per feature block; 605 = 5 * 121
#define NTILES 121
#define NCHUNK 8
#define CHPTS  (NPTS / NCHUNK)   // 2048

// ---------------------------------------------------------------------------
// Kernel 1a: rotation-voxel partial histograms.
// grid = 64 (a,b) * NCHUNK point-chunks = 512 blocks.  LDS-private histogram,
// then integer atomicAdd into ws (zeroed each call) -> deterministic.
// ---------------------------------------------------------------------------
__global__ __launch_bounds__(256) void rot_part_kernel(const float* __restrict__ pcd,
                                                       int* __restrict__ wshist) {
    __shared__ int h[LVOX];
    const int bid   = blockIdx.x;
    const int ab    = bid & 63;        // a*8 + b
    const int chunk = bid >> 6;
    const int a     = ab >> 3;
    const int b     = ab & 7;
    const int tid   = threadIdx.x;

    for (int i = tid; i < LVOX; i += 256) h[i] = 0;
    __syncthreads();

    const float C[8] = { -4.3711388e-08f, 0.3826834323650898f, 0.7071067811865476f,
                         0.9238795325112867f, 1.0f, 0.9238795325112867f,
                         0.7071067811865476f, 0.3826834323650898f };
    const float S[8] = { -1.0f, -0.9238795325112867f, -0.7071067811865476f,
                         -0.3826834323650898f, 0.0f, 0.3826834323650898f,
                         0.7071067811865476f, 0.9238795325112867f };
    const float c = C[a];
    const float s = S[a];

    const float* __restrict__ p = pcd + ((size_t)b * NPTS + (size_t)chunk * CHPTS) * 3;

    for (int n = tid; n < CHPTS; n += 256) {
        const float x = p[n * 3 + 0];
        const float y = p[n * 3 + 1];
        const float z = p[n * 3 + 2];
        const float rx = x * c - y * s + 5.5f;
        const float ry = x * s + y * c + 5.5f;
        const float rz = z + 2.5f;
        const int icx = (int)floorf(rx);
        const int icy = (int)floorf(ry);
        const int icz = (int)floorf(rz);
        const int flat = icz + icy * 5 + icx * 55;
        if (flat >= 0 && flat < LVOX) atomicAdd(&h[flat], 1);
    }
    __syncthreads();

    int* __restrict__ dst = wshist + (size_t)ab * LVOX;
    for (int i = tid; i < LVOX; i += 256) {
        const int v = h[i];
        if (v) atomicAdd(&dst[i], v);
    }
}

// ---------------------------------------------------------------------------
// Kernel 1b: write rot histogram channels 15..22 from ws.
// ---------------------------------------------------------------------------
__global__ __launch_bounds__(256) void rot_write_kernel(const int* __restrict__ wshist,
                                                        float* __restrict__ out) {
    const int idx = blockIdx.x * 256 + threadIdx.x;
    const int TOT = ABINS * BATCH * LVOX;
    if (idx >= TOT) return;
    const int a   = idx / (BATCH * LVOX);
    const int rem = idx % (BATCH * LVOX);
    const int b   = rem / LVOX;
    const int l   = rem % LVOX;
    const int v   = wshist[((size_t)a * BATCH + b) * LVOX + l];
    out[((size_t)b * LVOX + l) * CH + 15 + a] = (float)v * (1.0f / (float)NPTS);
}

// ---------------------------------------------------------------------------
// Kernel 2: cumulative distance features, 5 locs per block.
// d2 <= (q+1)^2  <=>  |p|^2 - 2 p.loc + |loc|^2 <= (q+1)^2  (literal consts).
// Per (point,loc): 3 FMA + 1 add + 15 cmp + 15 addc; point load + |p|^2
// amortized over 5 locs.  cnt[5][15] fully unrolled -> registers.
// ---------------------------------------------------------------------------
__global__ __launch_bounds__(256) void feature_kernel(const float* __restrict__ pcd,
                                                      float* __restrict__ out) {
    const int bid  = blockIdx.x;
    const int b    = bid / NTILES;
    const int tile = bid % NTILES;
    const int l0   = tile * TLOC;

    float m2lx[TLOC], m2ly[TLOC], m2lz[TLOC], ll[TLOC];
#pragma unroll
    for (int i = 0; i < TLOC; ++i) {
        const int l  = l0 + i;
        const int gi = l / 55;
        const int gj = (l / 5) % 11;
        const int gk = l % 5;
        const float lx = -5.0f + (float)gi;
        const float ly = -5.0f + (float)gj;
        const float lz = -2.0f + (float)gk;
        m2lx[i] = -2.0f * lx;
        m2ly[i] = -2.0f * ly;
        m2lz[i] = -2.0f * lz;
        ll[i]   = lx * lx + ly * ly + lz * lz;
    }

    int cnt[TLOC][15];
#pragma unroll
    for (int i = 0; i < TLOC; ++i)
#pragma unroll
        for (int q = 0; q < 15; ++q) cnt[i][q] = 0;

    const float* __restrict__ p = pcd + (size_t)b * NPTS * 3;

#pragma unroll 2
    for (int n = threadIdx.x; n < NPTS; n += 256) {
        const float x = p[n * 3 + 0];
        const float y = p[n * 3 + 1];
        const float z = p[n * 3 + 2];
        const float s = fmaf(x, x, fmaf(y, y, z * z));
#pragma unroll
        for (int i = 0; i < TLOC; ++i) {
            const float u = fmaf(x, m2lx[i], fmaf(y, m2ly[i], fmaf(z, m2lz[i], s))) + ll[i];
#pragma unroll
            for (int q = 0; q < 15; ++q) {
                const float thr = (float)((q + 1) * (q + 1));
                cnt[i][q] += (u <= thr) ? 1 : 0;
            }
        }
    }

    // 64-lane butterfly reduce each counter
#pragma unroll
    for (int i = 0; i < TLOC; ++i)
#pragma unroll
        for (int q = 0; q < 15; ++q)
#pragma unroll
            for (int off = 32; off > 0; off >>= 1)
                cnt[i][q] += __shfl_xor(cnt[i][q], off);

    __shared__ int wsum[4][TLOC * 15];
    const int wid  = threadIdx.x >> 6;
    const int lane = threadIdx.x & 63;
    if (lane == 0) {
#pragma unroll
        for (int i = 0; i < TLOC; ++i)
#pragma unroll
            for (int q = 0; q < 15; ++q) wsum[wid][i * 15 + q] = cnt[i][q];
    }
    __syncthreads();

    const int t = threadIdx.x;
    if (t < TLOC * 15) {
        const int tot = wsum[0][t] + wsum[1][t] + wsum[2][t] + wsum[3][t];
        const int i = t / 15;
        const int q = t % 15;
        out[((size_t)b * LVOX + (l0 + i)) * CH + q] = (float)tot * (1.0f / (float)NPTS);
    }
}

extern "C" void kernel_launch(void* const* d_in, const int* in_sizes, int n_in,
                              void* d_out, int out_size, void* d_ws, size_t ws_size,
                              hipStream_t stream) {
    const float* pcd = (const float*)d_in[0];
    float* out = (float*)d_out;
    int* wshist = (int*)d_ws;   // 64 * 605 ints = 155 KB

    hipMemsetAsync(wshist, 0, (size_t)ABINS * BATCH * LVOX * sizeof(int), stream);
    hipLaunchKernelGGL(rot_part_kernel, dim3(64 * NCHUNK), dim3(256), 0, stream,
                       pcd, wshist);
    hipLaunchKernelGGL(feature_kernel, dim3(BATCH * NTILES), dim3(256), 0, stream,
                       pcd, out);
    hipLaunchKernelGGL(rot_write_kernel, dim3((ABINS * BATCH * LVOX + 255) / 256),
                       dim3(256), 0, stream, wshist, out);
}

// Round 3
// 84.537 us; speedup vs baseline: 4.2016x; 4.2016x over previous
//
#include <hip/hip_runtime.h>

#define BATCH  8
#define NPTS   16384
#define LVOX   605     // 11*11*5
#define ABINS  8
#define CH     23
#define LTILE  121     // locs per tile; 605 = 5*121
#define NTILE  5
#define NOUT   16      // outer point chunks per (b,tile)
#define BPTS   1024    // points per block (4 subchunks * 256)
#define SPTS   256     // points per subchunk
#define NCHUNK 8       // rot kernel point chunks
#define CHPTS  (NPTS / NCHUNK)

// ws layout: [0, 64*605) rot hist ints; [64*605, +8*605*16) feature hist ints
#define ROT_WS_INTS  (ABINS * BATCH * LVOX)          // 38720
#define FEAT_WS_INTS (BATCH * LVOX * 16)             // 77440

// ---------------------------------------------------------------------------
// Kernel 1: rotation-voxel partial histograms (proven in R1/R2).
// ---------------------------------------------------------------------------
__global__ __launch_bounds__(256) void rot_part_kernel(const float* __restrict__ pcd,
                                                       int* __restrict__ wshist) {
    __shared__ int h[LVOX];
    const int bid   = blockIdx.x;
    const int ab    = bid & 63;        // a*8 + b
    const int chunk = bid >> 6;
    const int a     = ab >> 3;
    const int b     = ab & 7;
    const int tid   = threadIdx.x;

    for (int i = tid; i < LVOX; i += 256) h[i] = 0;
    __syncthreads();

    const float C[8] = { -4.3711388e-08f, 0.3826834323650898f, 0.7071067811865476f,
                         0.9238795325112867f, 1.0f, 0.9238795325112867f,
                         0.7071067811865476f, 0.3826834323650898f };
    const float S[8] = { -1.0f, -0.9238795325112867f, -0.7071067811865476f,
                         -0.3826834323650898f, 0.0f, 0.3826834323650898f,
                         0.7071067811865476f, 0.9238795325112867f };
    const float c = C[a];
    const float s = S[a];

    const float* __restrict__ p = pcd + ((size_t)b * NPTS + (size_t)chunk * CHPTS) * 3;

    for (int n = tid; n < CHPTS; n += 256) {
        const float x = p[n * 3 + 0];
        const float y = p[n * 3 + 1];
        const float z = p[n * 3 + 2];
        const float rx = x * c - y * s + 5.5f;
        const float ry = x * s + y * c + 5.5f;
        const float rz = z + 2.5f;
        const int icx = (int)floorf(rx);
        const int icy = (int)floorf(ry);
        const int icz = (int)floorf(rz);
        const int flat = icz + icy * 5 + icx * 55;
        if (flat >= 0 && flat < LVOX) atomicAdd(&h[flat], 1);
    }
    __syncthreads();

    int* __restrict__ dst = wshist + (size_t)ab * LVOX;
    for (int i = tid; i < LVOX; i += 256) {
        const int v = h[i];
        if (v) atomicAdd(&dst[i], v);
    }
}

// ---------------------------------------------------------------------------
// Kernel 2: distance-bin partial histograms.
// One loc per thread; points via wave-uniform scalar loads; 4-bit packed
// nibble counters unpacked every 15 points; LDS 4-way reduce; int atomics.
// ---------------------------------------------------------------------------
__global__ __launch_bounds__(512) void feature_part_kernel(const float* __restrict__ pcd,
                                                           int* __restrict__ feat_hist) {
    const int bid   = blockIdx.x;
    const int b     = bid / (NTILE * NOUT);
    const int rem   = bid % (NTILE * NOUT);
    const int tile  = rem / NOUT;
    const int outer = rem % NOUT;
    const int tid   = threadIdx.x;
    // sub is wave-uniform (waves of 64; 128-thread groups); readfirstlane makes
    // it *provably* uniform so the point pointer scalarizes to s_load.
    const int sub = __builtin_amdgcn_readfirstlane(tid >> 7);
    const int li  = tid & 127;
    const int lc  = (li < LTILE) ? li : (LTILE - 1);
    const int l   = tile * LTILE + lc;
    const int gi = l / 55, gj = (l / 5) % 11, gk = l % 5;
    const float lx = -5.0f + (float)gi;
    const float ly = -5.0f + (float)gj;
    const float lz = -2.0f + (float)gk;

    const float* __restrict__ pp =
        pcd + ((size_t)b * NPTS + (size_t)outer * BPTS + (size_t)sub * SPTS) * 3;

    int cnt[16];
#pragma unroll
    for (int q = 0; q < 16; ++q) cnt[q] = 0;

    unsigned long long packed = 0;

#define PROCESS_PT(IDX)                                                        \
    {                                                                          \
        const float x = pp[(IDX) * 3 + 0];                                     \
        const float y = pp[(IDX) * 3 + 1];                                     \
        const float z = pp[(IDX) * 3 + 2];                                     \
        const float dx = x - lx, dy = y - ly, dz = z - lz;                     \
        const float d2 = fmaf(dx, dx, fmaf(dy, dy, dz * dz));                  \
        const float d  = __builtin_amdgcn_sqrtf(d2);                           \
        const float kf = fminf(fmaxf(__builtin_ceilf(d), 1.0f), 16.0f);        \
        const int   k  = (int)kf;                                              \
        packed += 1ull << ((k << 2) - 4);                                      \
    }

#define UNPACK()                                                               \
    {                                                                          \
        const unsigned lo = (unsigned)packed;                                  \
        const unsigned hi = (unsigned)(packed >> 32);                          \
        _Pragma("unroll")                                                      \
        for (int f = 0; f < 8; ++f) cnt[f]     += (int)((lo >> (4 * f)) & 15u);\
        _Pragma("unroll")                                                      \
        for (int f = 0; f < 8; ++f) cnt[8 + f] += (int)((hi >> (4 * f)) & 15u);\
        packed = 0;                                                            \
    }

#pragma unroll 1
    for (int g = 0; g < 17; ++g) {     // 17 groups of 15 points = 255
#pragma unroll
        for (int j = 0; j < 15; ++j) {
            PROCESS_PT(g * 15 + j);
        }
        UNPACK();
    }
    PROCESS_PT(255);                   // last point
    UNPACK();

    // LDS reduce across the 4 subchunks sharing each loc
    __shared__ int red[512 * 16];      // 32 KB
    const int base = tid * 16;
#pragma unroll
    for (int q = 0; q < 16; ++q) red[base + q] = cnt[q];
    __syncthreads();

    if (tid < 128) {
        int acc[16];
#pragma unroll
        for (int q = 0; q < 16; ++q) {
            acc[q] = red[(0 * 128 + tid) * 16 + q] + red[(1 * 128 + tid) * 16 + q] +
                     red[(2 * 128 + tid) * 16 + q] + red[(3 * 128 + tid) * 16 + q];
        }
        if (tid < LTILE) {
            const int ll = tile * LTILE + tid;
            int* __restrict__ dst = feat_hist + ((size_t)b * LVOX + ll) * 16;
#pragma unroll
            for (int q = 0; q < 16; ++q) atomicAdd(&dst[q], acc[q]);
        }
    }
#undef PROCESS_PT
#undef UNPACK
}

// ---------------------------------------------------------------------------
// Kernel 3: finalize.  16-lane groups: lane q holds hist bin q for one (b,l);
// inclusive prefix scan over lanes 0..q gives feature[q]; lanes 0..7 also
// write the 8 rot channels.
// ---------------------------------------------------------------------------
__global__ __launch_bounds__(256) void write_kernel(const int* __restrict__ rot_hist,
                                                    const int* __restrict__ feat_hist,
                                                    float* __restrict__ out) {
    const int gt    = blockIdx.x * 256 + threadIdx.x;
    const int group = gt >> 4;                 // (b,l)
    const int q     = gt & 15;
    if (group >= BATCH * LVOX) return;
    const int b = group / LVOX;
    const int l = group % LVOX;

    int v = feat_hist[(size_t)group * 16 + q];
#pragma unroll
    for (int off = 1; off < 16; off <<= 1) {
        const int t = __shfl_up(v, off, 16);
        if (q >= off) v += t;
    }
    const float inv_n = 1.0f / (float)NPTS;
    float* __restrict__ o = out + (size_t)group * CH;
    if (q < 15) o[q] = (float)v * inv_n;
    if (q < 8) {
        const int r = rot_hist[((size_t)q * BATCH + b) * LVOX + l];
        o[15 + q] = (float)r * inv_n;
    }
}

extern "C" void kernel_launch(void* const* d_in, const int* in_sizes, int n_in,
                              void* d_out, int out_size, void* d_ws, size_t ws_size,
                              hipStream_t stream) {
    const float* pcd = (const float*)d_in[0];
    float* out = (float*)d_out;
    int* rot_hist  = (int*)d_ws;
    int* feat_hist = rot_hist + ROT_WS_INTS;

    hipMemsetAsync(d_ws, 0, (size_t)(ROT_WS_INTS + FEAT_WS_INTS) * sizeof(int), stream);
    hipLaunchKernelGGL(rot_part_kernel, dim3(64 * NCHUNK), dim3(256), 0, stream,
                       pcd, rot_hist);
    hipLaunchKernelGGL(feature_part_kernel, dim3(BATCH * NTILE * NOUT), dim3(512), 0,
                       stream, pcd, feat_hist);
    hipLaunchKernelGGL(write_kernel, dim3((BATCH * LVOX * 16 + 255) / 256), dim3(256),
                       0, stream, rot_hist, feat_hist, out);
}

// Round 4
// 53.771 us; speedup vs baseline: 6.6057x; 1.5722x over previous
//
#include <hip/hip_runtime.h>

#define BATCH  8
#define NPTS   16384
#define LVOX   605     // 11*11*5
#define ABINS  8
#define CH     23
#define LTILE  121
#define NTILE  5
#define NOUT   64      // point chunks per (b,tile)
#define BPTS   256     // points per feature block
#define SPTS   128     // points per subchunk (per thread)
#define NCHUNK 8
#define CHPTS  (NPTS / NCHUNK)   // 2048

#define FEAT_BLOCKS (BATCH * NTILE * NOUT)    // 2560
#define ROT_BLOCKS  (ABINS * BATCH * NCHUNK)  // 512

#define ROT_WS_INTS  (ABINS * BATCH * LVOX)   // 38720 ints
#define FEAT_WS_ULL  (BATCH * LVOX * 4)       // 19360 ull (16-bit packed x4)

// ---------------------------------------------------------------------------
// Fused kernel: blocks [0,2560) distance features; [2560,3072) rot histogram.
// ---------------------------------------------------------------------------
__global__ __launch_bounds__(256) void main_kernel(const float* __restrict__ pcd,
                                                   int* __restrict__ rot_hist,
                                                   unsigned long long* __restrict__ feat_hist) {
    __shared__ int smem[16 * 128];   // 8 KB; reused as rot histogram (605 ints)
    const int bid = blockIdx.x;
    const int tid = threadIdx.x;

    if (bid < FEAT_BLOCKS) {
        // ------------------ distance-bin features ------------------
        const int b     = bid / (NTILE * NOUT);
        const int rem   = bid % (NTILE * NOUT);
        const int tile  = rem / NOUT;
        const int outer = rem % NOUT;
        // sub is constant within each 64-lane wave; readfirstlane proves it
        // uniform so the point pointer scalarizes to s_load.
        const int sub = __builtin_amdgcn_readfirstlane(tid >> 7);
        const int li  = tid & 127;
        const int lc  = (li < LTILE) ? li : (LTILE - 1);
        const int l   = tile * LTILE + lc;
        const int gi = l / 55, gj = (l / 5) % 11, gk = l % 5;
        const float lx = -5.0f + (float)gi;
        const float ly = -5.0f + (float)gj;
        const float lz = -2.0f + (float)gk;

        const float* __restrict__ pp =
            pcd + ((size_t)b * NPTS + outer * BPTS + sub * SPTS) * 3;

        unsigned long long bytes_e = 0, bytes_o = 0;

        // k = floor(sqrt(d2)) == ceil(d)-1 except at measure-zero integer d.
        // nibble index k in packed 64-bit; merged to byte counters per group.
#define PT(NIB, IDX)                                                           \
        {                                                                      \
            const float x = pp[(IDX) * 3 + 0];                                 \
            const float y = pp[(IDX) * 3 + 1];                                 \
            const float z = pp[(IDX) * 3 + 2];                                 \
            const float dx = x - lx, dy = y - ly, dz = z - lz;                 \
            const float d2 = fmaf(dx, dx, fmaf(dy, dy, dz * dz));              \
            const float d  = __builtin_amdgcn_sqrtf(d2);                       \
            int k = (int)d;                                                    \
            k = (k < 15) ? k : 15;                                             \
            NIB += 1ull << (k << 2);                                           \
        }

#pragma unroll 1
        for (int g = 0; g < 8; ++g) {        // 8 groups of 15 points
            unsigned long long nib = 0;
#pragma unroll
            for (int j = 0; j < 15; ++j) PT(nib, g * 15 + j)
            bytes_e += nib & 0x0F0F0F0F0F0F0F0Full;
            bytes_o += (nib >> 4) & 0x0F0F0F0F0F0F0F0Full;
        }
        {
            unsigned long long nib = 0;       // tail: points 120..127
#pragma unroll
            for (int j = 120; j < 128; ++j) PT(nib, j)
            bytes_e += nib & 0x0F0F0F0F0F0F0F0Full;
            bytes_o += (nib >> 4) & 0x0F0F0F0F0F0F0F0Full;
        }
#undef PT

        int acc[16];
#pragma unroll
        for (int j = 0; j < 8; ++j) {
            acc[2 * j]     = (int)((bytes_e >> (8 * j)) & 0xFFull);
            acc[2 * j + 1] = (int)((bytes_o >> (8 * j)) & 0xFFull);
        }

        // conflict-free LDS reduce: layout [bin][loc], lanes -> consecutive banks
        if (tid >= 128) {
#pragma unroll
            for (int q = 0; q < 16; ++q) smem[q * 128 + li] = acc[q];
        }
        __syncthreads();
        if (tid < LTILE) {
            unsigned long long* __restrict__ dst =
                feat_hist + ((size_t)b * LVOX + tile * LTILE + tid) * 4;
#pragma unroll
            for (int j = 0; j < 4; ++j) {
                const unsigned long long v0 = (unsigned)(acc[4*j]   + smem[(4*j)*128   + tid]);
                const unsigned long long v1 = (unsigned)(acc[4*j+1] + smem[(4*j+1)*128 + tid]);
                const unsigned long long v2 = (unsigned)(acc[4*j+2] + smem[(4*j+2)*128 + tid]);
                const unsigned long long v3 = (unsigned)(acc[4*j+3] + smem[(4*j+3)*128 + tid]);
                atomicAdd(&dst[j], v0 | (v1 << 16) | (v2 << 32) | (v3 << 48));
            }
        }
    } else {
        // ------------------ rotation-voxel histogram ------------------
        const int rb    = bid - FEAT_BLOCKS;
        const int ab    = rb & 63;         // a*8 + b
        const int chunk = rb >> 6;
        const int a     = ab >> 3;
        const int b     = ab & 7;

        int* h = smem;
        for (int i = tid; i < LVOX; i += 256) h[i] = 0;
        __syncthreads();

        const float C[8] = { -4.3711388e-08f, 0.3826834323650898f, 0.7071067811865476f,
                             0.9238795325112867f, 1.0f, 0.9238795325112867f,
                             0.7071067811865476f, 0.3826834323650898f };
        const float S[8] = { -1.0f, -0.9238795325112867f, -0.7071067811865476f,
                             -0.3826834323650898f, 0.0f, 0.3826834323650898f,
                             0.7071067811865476f, 0.9238795325112867f };
        const float c = C[a];
        const float s = S[a];

        const float* __restrict__ p = pcd + ((size_t)b * NPTS + (size_t)chunk * CHPTS) * 3;

        for (int n = tid; n < CHPTS; n += 256) {
            const float x = p[n * 3 + 0];
            const float y = p[n * 3 + 1];
            const float z = p[n * 3 + 2];
            const float rx = x * c - y * s + 5.5f;
            const float ry = x * s + y * c + 5.5f;
            const float rz = z + 2.5f;
            const int icx = (int)floorf(rx);
            const int icy = (int)floorf(ry);
            const int icz = (int)floorf(rz);
            const int flat = icz + icy * 5 + icx * 55;
            if (flat >= 0 && flat < LVOX) atomicAdd(&h[flat], 1);
        }
        __syncthreads();

        int* __restrict__ dst = rot_hist + (size_t)ab * LVOX;
        for (int i = tid; i < LVOX; i += 256) {
            const int v = h[i];
            if (v) atomicAdd(&dst[i], v);
        }
    }
}

// ---------------------------------------------------------------------------
// Finalize: 16-lane groups; prefix-scan packed 16-bit bins; write both parts.
// ---------------------------------------------------------------------------
__global__ __launch_bounds__(256) void write_kernel(const int* __restrict__ rot_hist,
                                                    const unsigned* __restrict__ feat_hist32,
                                                    float* __restrict__ out) {
    const int gt    = blockIdx.x * 256 + threadIdx.x;
    const int group = gt >> 4;                 // (b,l)
    const int q     = gt & 15;
    if (group >= BATCH * LVOX) return;
    const int b = group / LVOX;
    const int l = group % LVOX;

    const unsigned word = feat_hist32[(size_t)group * 8 + (q >> 1)];
    int v = (int)((word >> (16 * (q & 1))) & 0xFFFFu);
#pragma unroll
    for (int off = 1; off < 16; off <<= 1) {
        const int t = __shfl_up(v, off, 16);
        if (q >= off) v += t;
    }
    const float inv_n = 1.0f / (float)NPTS;
    float* __restrict__ o = out + (size_t)group * CH;
    if (q < 15) o[q] = (float)v * inv_n;
    if (q < 8) {
        const int r = rot_hist[((size_t)q * BATCH + b) * LVOX + l];
        o[15 + q] = (float)r * inv_n;
    }
}

extern "C" void kernel_launch(void* const* d_in, const int* in_sizes, int n_in,
                              void* d_out, int out_size, void* d_ws, size_t ws_size,
                              hipStream_t stream) {
    const float* pcd = (const float*)d_in[0];
    float* out = (float*)d_out;
    int* rot_hist = (int*)d_ws;
    unsigned long long* feat_hist =
        (unsigned long long*)((char*)d_ws + (size_t)ROT_WS_INTS * sizeof(int));

    hipMemsetAsync(d_ws, 0,
                   (size_t)ROT_WS_INTS * sizeof(int) + (size_t)FEAT_WS_ULL * 8, stream);
    hipLaunchKernelGGL(main_kernel, dim3(FEAT_BLOCKS + ROT_BLOCKS), dim3(256), 0,
                       stream, pcd, rot_hist, feat_hist);
    hipLaunchKernelGGL(write_kernel, dim3((BATCH * LVOX * 16 + 255) / 256), dim3(256),
                       0, stream, rot_hist, (const unsigned*)feat_hist, out);
}

// Round 5
// 44.947 us; speedup vs baseline: 7.9025x; 1.1963x over previous
//
#include <hip/hip_runtime.h>

#define BATCH  8
#define NPTS   16384
#define LVOX   605     // 11*11*5 = 121 xy-columns * 5 z
#define ABINS  8
#define CH     23
#define NCOL   121
#define SPTS   64      // points per 128-lane group
#define GRPS   4       // groups per block (512 threads)
#define BPTS   (SPTS * GRPS)          // 256 points per feature block
#define FEAT_BLOCKS (BATCH * (NPTS / BPTS))   // 8*64 = 512
#define ROT_CH    4
#define ROT_CHPTS (NPTS / ROT_CH)             // 4096
#define ROT_BLOCKS (ABINS * BATCH * ROT_CH)   // 256

#define ROT_WS_INTS (ABINS * BATCH * LVOX)    // 38720 ints
#define FEAT_WS_ULL (BATCH * LVOX * 4)        // 19360 ull (4x16-bit packed)

#define MASK8  0x0F0F0F0F0F0F0F0Full
#define MASK16 0x00FF00FF00FF00FFull

// ---------------------------------------------------------------------------
// Fused kernel, 512 threads.  Blocks [0,512): distance features.  Each
// 128-lane group: lane = xy-column (121 of 128), 5 z-locs per lane sharing
// rxy2; 64 points per group via wave-uniform scalar loads.  Nibble-packed
// bins -> byte counters -> LDS combine -> packed-16-bit global atomics.
// Blocks [512,768): rotation-voxel histogram (a,b) x 4 point chunks.
// ---------------------------------------------------------------------------
__global__ __launch_bounds__(512) void main_kernel(const float* __restrict__ pcd,
                                                   int* __restrict__ rot_hist,
                                                   unsigned long long* __restrict__ feat_hist) {
    __shared__ unsigned long long lds[5][2][4][129];   // 41.3 KB (129 pad: banks)
    const int bid = blockIdx.x;
    const int tid = threadIdx.x;

    if (bid < FEAT_BLOCKS) {
        const int b     = bid >> 6;      // /64
        const int outer = bid & 63;
        // group id is wave-uniform (128 = 2 waves); prove it for s_load.
        const int g4 = __builtin_amdgcn_readfirstlane(tid >> 7);
        const int li = tid & 127;
        const int cc = (li < NCOL) ? li : (NCOL - 1);
        const float lx = -5.0f + (float)(cc / 11);
        const float ly = -5.0f + (float)(cc % 11);

        const float* __restrict__ pp =
            pcd + ((size_t)b * NPTS + outer * BPTS + g4 * SPTS) * 3;

        unsigned long long be0 = 0, bo0 = 0, be1 = 0, bo1 = 0, be2 = 0, bo2 = 0,
                           be3 = 0, bo3 = 0, be4 = 0, bo4 = 0;

        // bin = floor(d) (== ceil(d)-1 a.e.); geometry => bin <= 13, no clamp.
#define PT(J)                                                                   \
        {                                                                       \
            const float x  = pp[(J) * 3 + 0];                                   \
            const float y  = pp[(J) * 3 + 1];                                   \
            const float zp = pp[(J) * 3 + 2];                                   \
            const float dx = x - lx, dy = y - ly;                               \
            const float rxy2 = fmaf(dy, dy, dx * dx);                           \
            const float dz0 = zp + 2.0f;                                        \
            { const float dz = dz0;        const float d = __builtin_amdgcn_sqrtf(fmaf(dz, dz, rxy2)); n0 += 1ull << (((int)d) << 2); } \
            { const float dz = dz0 - 1.0f; const float d = __builtin_amdgcn_sqrtf(fmaf(dz, dz, rxy2)); n1 += 1ull << (((int)d) << 2); } \
            { const float dz = dz0 - 2.0f; const float d = __builtin_amdgcn_sqrtf(fmaf(dz, dz, rxy2)); n2 += 1ull << (((int)d) << 2); } \
            { const float dz = dz0 - 3.0f; const float d = __builtin_amdgcn_sqrtf(fmaf(dz, dz, rxy2)); n3 += 1ull << (((int)d) << 2); } \
            { const float dz = dz0 - 4.0f; const float d = __builtin_amdgcn_sqrtf(fmaf(dz, dz, rxy2)); n4 += 1ull << (((int)d) << 2); } \
        }

#define MERGE()                                                                 \
        be0 += n0 & MASK8; bo0 += (n0 >> 4) & MASK8;                            \
        be1 += n1 & MASK8; bo1 += (n1 >> 4) & MASK8;                            \
        be2 += n2 & MASK8; bo2 += (n2 >> 4) & MASK8;                            \
        be3 += n3 & MASK8; bo3 += (n3 >> 4) & MASK8;                            \
        be4 += n4 & MASK8; bo4 += (n4 >> 4) & MASK8;

#pragma unroll 1
        for (int grp = 0; grp < 4; ++grp) {       // 4 groups of 15 points
            const int base = grp * 15;
            unsigned long long n0 = 0, n1 = 0, n2 = 0, n3 = 0, n4 = 0;
#pragma unroll
            for (int j = 0; j < 15; ++j) PT(base + j)
            MERGE()
        }
        {                                          // tail: points 60..63
            unsigned long long n0 = 0, n1 = 0, n2 = 0, n3 = 0, n4 = 0;
#pragma unroll
            for (int j = 60; j < 64; ++j) PT(j)
            MERGE()
        }
#undef PT
#undef MERGE

        lds[0][0][g4][li] = be0;  lds[0][1][g4][li] = bo0;
        lds[1][0][g4][li] = be1;  lds[1][1][g4][li] = bo1;
        lds[2][0][g4][li] = be2;  lds[2][1][g4][li] = bo2;
        lds[3][0][g4][li] = be3;  lds[3][1][g4][li] = bo3;
        lds[4][0][g4][li] = be4;  lds[4][1][g4][li] = bo4;
        __syncthreads();

        // combine 4 groups (byte domain -> 16-bit domain), 2 atomics per item
        for (int item = tid; item < LVOX * 2; item += 512) {
            const int loc = item >> 1;
            const int eo  = item & 1;
            const int col = loc / 5;
            const int z   = loc % 5;
            unsigned long long slo = 0, shi = 0;
#pragma unroll
            for (int g = 0; g < 4; ++g) {
                const unsigned long long v = lds[z][eo][g][col];
                slo += v & MASK16;
                shi += (v >> 8) & MASK16;
            }
            unsigned long long* __restrict__ dst =
                feat_hist + ((size_t)b * LVOX + loc) * 4 + eo * 2;
            atomicAdd(&dst[0], slo);
            atomicAdd(&dst[1], shi);
        }
    } else {
        // ------------------ rotation-voxel histogram ------------------
        const int rb    = bid - FEAT_BLOCKS;
        const int ab    = rb & 63;        // a*8 + b
        const int chunk = rb >> 6;        // 0..3
        const int a     = ab >> 3;
        const int b     = ab & 7;

        int* h = (int*)lds;
        for (int i = tid; i < LVOX; i += 512) h[i] = 0;
        __syncthreads();

        const float C[8] = { -4.3711388e-08f, 0.3826834323650898f, 0.7071067811865476f,
                             0.9238795325112867f, 1.0f, 0.9238795325112867f,
                             0.7071067811865476f, 0.3826834323650898f };
        const float S[8] = { -1.0f, -0.9238795325112867f, -0.7071067811865476f,
                             -0.3826834323650898f, 0.0f, 0.3826834323650898f,
                             0.7071067811865476f, 0.9238795325112867f };
        const float c = C[a];
        const float s = S[a];

        const float* __restrict__ p =
            pcd + ((size_t)b * NPTS + (size_t)chunk * ROT_CHPTS) * 3;

        for (int n = tid; n < ROT_CHPTS; n += 512) {
            const float x = p[n * 3 + 0];
            const float y = p[n * 3 + 1];
            const float z = p[n * 3 + 2];
            const float rx = x * c - y * s + 5.5f;
            const float ry = x * s + y * c + 5.5f;
            const float rz = z + 2.5f;
            const int icx = (int)floorf(rx);
            const int icy = (int)floorf(ry);
            const int icz = (int)floorf(rz);
            const int flat = icz + icy * 5 + icx * 55;
            if (flat >= 0 && flat < LVOX) atomicAdd(&h[flat], 1);
        }
        __syncthreads();

        int* __restrict__ dst = rot_hist + (size_t)ab * LVOX;
        for (int i = tid; i < LVOX; i += 512) {
            const int v = h[i];
            if (v) atomicAdd(&dst[i], v);
        }
    }
}

// ---------------------------------------------------------------------------
// Finalize.  16-lane groups; bin q lives in ull word w = ((q&1)<<1)|((q>>1)&1),
// 16-bit slot q>>2.  Prefix-scan, write features + rot channels.
// ---------------------------------------------------------------------------
__global__ __launch_bounds__(256) void write_kernel(const int* __restrict__ rot_hist,
                                                    const unsigned* __restrict__ feat_hist32,
                                                    float* __restrict__ out) {
    const int gt    = blockIdx.x * 256 + threadIdx.x;
    const int group = gt >> 4;                 // (b,l)
    const int q     = gt & 15;
    if (group >= BATCH * LVOX) return;
    const int b = group / LVOX;
    const int l = group % LVOX;

    const int w    = ((q & 1) << 1) | ((q >> 1) & 1);
    const int slot = q >> 2;
    const unsigned word = feat_hist32[(size_t)group * 8 + w * 2 + (slot >> 1)];
    int v = (int)((word >> (16 * (slot & 1))) & 0xFFFFu);
#pragma unroll
    for (int off = 1; off < 16; off <<= 1) {
        const int t = __shfl_up(v, off, 16);
        if (q >= off) v += t;
    }
    const float inv_n = 1.0f / (float)NPTS;
    float* __restrict__ o = out + (size_t)group * CH;
    if (q < 15) o[q] = (float)v * inv_n;
    if (q < 8) {
        const int r = rot_hist[((size_t)q * BATCH + b) * LVOX + l];
        o[15 + q] = (float)r * inv_n;
    }
}

extern "C" void kernel_launch(void* const* d_in, const int* in_sizes, int n_in,
                              void* d_out, int out_size, void* d_ws, size_t ws_size,
                              hipStream_t stream) {
    const float* pcd = (const float*)d_in[0];
    float* out = (float*)d_out;
    int* rot_hist = (int*)d_ws;
    unsigned long long* feat_hist =
        (unsigned long long*)((char*)d_ws + (size_t)ROT_WS_INTS * sizeof(int));

    hipMemsetAsync(d_ws, 0,
                   (size_t)ROT_WS_INTS * sizeof(int) + (size_t)FEAT_WS_ULL * 8, stream);
    hipLaunchKernelGGL(main_kernel, dim3(FEAT_BLOCKS + ROT_BLOCKS), dim3(512), 0,
                       stream, pcd, rot_hist, feat_hist);
    hipLaunchKernelGGL(write_kernel, dim3((BATCH * LVOX * 16 + 255) / 256), dim3(256),
                       0, stream, rot_hist, (const unsigned*)feat_hist, out);
}